// Round 1
// baseline (1126.700 us; speedup 1.0000x reference)
//
#include <hip/hip_runtime.h>
#include <hip/hip_bf16.h>
#include <math.h>

#define B_  2
#define S_  2048
#define H_  16
#define D_  1024
#define DK_ 64

__device__ __forceinline__ float f4get(const float4& v, int i) {
  return (i == 0) ? v.x : (i == 1) ? v.y : (i == 2) ? v.z : v.w;
}

// ---------------------------------------------------------------------------
// GEMM NT: C[m][n] = sum_k A[m][k] * W[n][k]
// 128x128 tile, TK=16, 256 threads. Thread tile = 2x2 quadrants of 4x4
// (rows {ty*4..+3, 64+ty*4..+3}, cols {tx*4..+3, 64+tx*4..+3}) so every LDS
// b128 read is either broadcast (A, ty-indexed) or lane-contiguous (B,
// tx-indexed) -> conflict-free.
// blockIdx.z selects which (W, C) pair (for fused QKV).
// ---------------------------------------------------------------------------
__global__ __launch_bounds__(256)
void gemm_nt(const float* __restrict__ A,
             const float* __restrict__ W0, const float* __restrict__ W1,
             const float* __restrict__ W2,
             float* __restrict__ C0, float* __restrict__ C1,
             float* __restrict__ C2,
             int M, int N, int K)
{
  const float* W = (blockIdx.z == 0) ? W0 : (blockIdx.z == 1) ? W1 : W2;
  float*       C = (blockIdx.z == 0) ? C0 : (blockIdx.z == 1) ? C1 : C2;

  // LDS stored K-major: As[kk][r]. Row stride 132 floats (33 16B-units, odd)
  // keeps kk-indexed reads on distinct bank columns.
  __shared__ float As[16][132];
  __shared__ float Bs[16][132];

  const int tid  = threadIdx.x;
  const int tx   = tid & 15;   // col quad 0..15
  const int ty   = tid >> 4;   // row quad 0..15
  const int row0 = blockIdx.y * 128;
  const int col0 = blockIdx.x * 128;

  float acc[2][2][4][4];
  #pragma unroll
  for (int a = 0; a < 2; ++a)
    #pragma unroll
    for (int b = 0; b < 2; ++b)
      #pragma unroll
      for (int i = 0; i < 4; ++i)
        #pragma unroll
        for (int j = 0; j < 4; ++j) acc[a][b][i][j] = 0.f;

  for (int k0 = 0; k0 < K; k0 += 16) {
    // stage A-tile (128x16) and W-tile (128x16), transposed into [kk][r]
    #pragma unroll
    for (int p = 0; p < 2; ++p) {
      int idx = tid + p * 256;        // 0..511
      int r   = idx >> 2;             // 0..127
      int kk4 = (idx & 3) << 2;       // 0,4,8,12
      float4 av = *(const float4*)(A + (size_t)(row0 + r) * K + k0 + kk4);
      As[kk4 + 0][r] = av.x; As[kk4 + 1][r] = av.y;
      As[kk4 + 2][r] = av.z; As[kk4 + 3][r] = av.w;
      float4 wv = *(const float4*)(W + (size_t)(col0 + r) * K + k0 + kk4);
      Bs[kk4 + 0][r] = wv.x; Bs[kk4 + 1][r] = wv.y;
      Bs[kk4 + 2][r] = wv.z; Bs[kk4 + 3][r] = wv.w;
    }
    __syncthreads();

    #pragma unroll
    for (int kk = 0; kk < 16; ++kk) {
      float4 a0 = *(const float4*)&As[kk][ty * 4];
      float4 a1 = *(const float4*)&As[kk][64 + ty * 4];
      float4 b0 = *(const float4*)&Bs[kk][tx * 4];
      float4 b1 = *(const float4*)&Bs[kk][64 + tx * 4];
      #pragma unroll
      for (int i = 0; i < 4; ++i) {
        float av0 = f4get(a0, i), av1 = f4get(a1, i);
        #pragma unroll
        for (int j = 0; j < 4; ++j) {
          float bv0 = f4get(b0, j), bv1 = f4get(b1, j);
          acc[0][0][i][j] += av0 * bv0;
          acc[0][1][i][j] += av0 * bv1;
          acc[1][0][i][j] += av1 * bv0;
          acc[1][1][i][j] += av1 * bv1;
        }
      }
    }
    __syncthreads();
  }

  #pragma unroll
  for (int ih = 0; ih < 2; ++ih)
    #pragma unroll
    for (int i = 0; i < 4; ++i) {
      int row = row0 + ih * 64 + ty * 4 + i;
      #pragma unroll
      for (int jh = 0; jh < 2; ++jh) {
        int col = col0 + jh * 64 + tx * 4;
        *(float4*)(C + (size_t)row * N + col) =
            make_float4(acc[ih][jh][i][0], acc[ih][jh][i][1],
                        acc[ih][jh][i][2], acc[ih][jh][i][3]);
      }
    }
}

// ---------------------------------------------------------------------------
// RoPE in-place on Q (grid.y==0) and K (grid.y==1), layout [B,S,D].
// Pair i of head h at row (b,s): (x[2i], x[2i+1]) rotated by pos * theta^(-2i/64).
// ---------------------------------------------------------------------------
__global__ __launch_bounds__(256)
void rope_kernel(float* __restrict__ q, float* __restrict__ k,
                 const int* __restrict__ pos)
{
  int t = blockIdx.x * 256 + threadIdx.x;        // 0 .. 2^21-1
  float* buf = (blockIdx.y == 0) ? q : k;
  int i  = t & 31;            // pair index in head
  int s  = (t >> 9) & 2047;   // sequence pos
  int b  = t >> 20;           // batch
  int p  = pos[(b << 11) | s];
  // freq_i = 10000^(-2i/64) = exp(-(2*ln(10000)/64) * i)
  float freq = __expf(-0.2878231366f * (float)i);
  float ang  = (float)p * freq;
  float sn, cs;
  sincosf(ang, &sn, &cs);
  size_t off = ((size_t)(t >> 5) << 6) + 2 * (size_t)i;  // rh*64 + 2i
  float2 v = *(float2*)(buf + off);
  float2 r;
  r.x = v.x * cs - v.y * sn;
  r.y = v.x * sn + v.y * cs;
  *(float2*)(buf + off) = r;
}

// ---------------------------------------------------------------------------
// Flash attention, fp32, causal. One block per (q-tile of 64, b*h).
// Q/K/V layout [B,S,D] with head offset h*64 (row stride D).
// 256 threads as 16x16; thread owns 4x4 of the 64x64 score tile and 4x4 of O.
// Online-softmax state (m,l) replicated across the 16 lanes of each row
// group; reduced with shfl_xor (width 16) — no LDS reductions.
// K staged transposed with XOR swizzle so tx-indexed b128 reads are
// conflict-free.
// ---------------------------------------------------------------------------
__global__ __launch_bounds__(256)
void attn_kernel(const float* __restrict__ Q, const float* __restrict__ K,
                 const float* __restrict__ V, float* __restrict__ O)
{
  const int qt  = blockIdx.x;        // 0..31
  const int b   = blockIdx.y >> 4;
  const int h   = blockIdx.y & 15;
  const int tid = threadIdx.x;
  const int tx  = tid & 15;
  const int ty  = tid >> 4;
  const int r0  = ty * 4;
  const int c0  = tx * 4;

  __shared__ float Qs[64][64];
  __shared__ float Kt[64 * 64];   // transposed + swizzled: (d,c) at d*64 + ((c>>2 ^ (d&15))<<2 | (c&3))
  __shared__ float Vs[64][64];
  __shared__ float Ps[64][64];

  const size_t base = (size_t)b * S_ * D_ + (size_t)h * DK_;

  // stage Q tile (once)
  #pragma unroll
  for (int it = 0; it < 4; ++it) {
    int idx = tid + it * 256;
    int rr  = idx >> 4;
    int d4  = (idx & 15) << 2;
    *(float4*)&Qs[rr][d4] =
        *(const float4*)(Q + base + (size_t)(qt * 64 + rr) * D_ + d4);
  }

  float Oacc[4][4];
  float m_i[4], l_i[4];
  #pragma unroll
  for (int i = 0; i < 4; ++i) {
    m_i[i] = -1e30f; l_i[i] = 0.f;
    #pragma unroll
    for (int j = 0; j < 4; ++j) Oacc[i][j] = 0.f;
  }

  for (int kt = 0; kt <= qt; ++kt) {
    __syncthreads();   // previous tile's PV reads done (and Q staging on kt=0)
    // stage K (transposed+swizzled) and V (natural)
    #pragma unroll
    for (int it = 0; it < 4; ++it) {
      int idx = tid + it * 256;
      int rr  = idx >> 4;             // key row 0..63
      int d4  = (idx & 15) << 2;
      float4 kv = *(const float4*)(K + base + (size_t)(kt * 64 + rr) * D_ + d4);
      #pragma unroll
      for (int p = 0; p < 4; ++p) {
        int d = d4 + p;
        Kt[d * 64 + ((((rr >> 2) ^ (d & 15)) << 2) | (rr & 3))] = f4get(kv, p);
      }
      *(float4*)&Vs[rr][d4] =
          *(const float4*)(V + base + (size_t)(kt * 64 + rr) * D_ + d4);
    }
    __syncthreads();

    // S = Q K^T (64x64x64)
    float sa[4][4];
    #pragma unroll
    for (int i = 0; i < 4; ++i)
      #pragma unroll
      for (int j = 0; j < 4; ++j) sa[i][j] = 0.f;

    #pragma unroll 4
    for (int d = 0; d < 64; d += 4) {
      float4 q4[4];
      #pragma unroll
      for (int i = 0; i < 4; ++i) q4[i] = *(const float4*)&Qs[r0 + i][d];
      #pragma unroll
      for (int p = 0; p < 4; ++p) {
        int dd = d + p;
        float4 k4 = *(const float4*)&Kt[dd * 64 + ((tx ^ (dd & 15)) << 2)];
        #pragma unroll
        for (int i = 0; i < 4; ++i) {
          float qv = f4get(q4[i], p);
          sa[i][0] += qv * k4.x;
          sa[i][1] += qv * k4.y;
          sa[i][2] += qv * k4.z;
          sa[i][3] += qv * k4.w;
        }
      }
    }

    // online softmax (per row, replicated across 16 lanes of the row group)
    const int rowg = qt * 64 + r0;
    const int colg = kt * 64 + c0;
    #pragma unroll
    for (int i = 0; i < 4; ++i) {
      float rmax = -1e30f;
      #pragma unroll
      for (int j = 0; j < 4; ++j) {
        float s = sa[i][j] * 0.125f;
        s = (colg + j <= rowg + i) ? s : -1e30f;
        sa[i][j] = s;
        rmax = fmaxf(rmax, s);
      }
      #pragma unroll
      for (int off = 1; off < 16; off <<= 1)
        rmax = fmaxf(rmax, __shfl_xor(rmax, off, 64));
      float mnew = fmaxf(m_i[i], rmax);
      float al   = __expf(m_i[i] - mnew);
      float rsum = 0.f;
      #pragma unroll
      for (int j = 0; j < 4; ++j) {
        float pv = __expf(sa[i][j] - mnew);
        sa[i][j] = pv;
        rsum += pv;
      }
      #pragma unroll
      for (int off = 1; off < 16; off <<= 1)
        rsum += __shfl_xor(rsum, off, 64);
      m_i[i] = mnew;
      l_i[i] = l_i[i] * al + rsum;
      #pragma unroll
      for (int j = 0; j < 4; ++j) Oacc[i][j] *= al;
      *(float4*)&Ps[r0 + i][c0] =
          make_float4(sa[i][0], sa[i][1], sa[i][2], sa[i][3]);
    }
    __syncthreads();   // Ps complete before PV

    // O += P * V (64x64x64)
    #pragma unroll 4
    for (int kk = 0; kk < 64; kk += 4) {
      float4 p4[4];
      #pragma unroll
      for (int i = 0; i < 4; ++i) p4[i] = *(const float4*)&Ps[r0 + i][kk];
      #pragma unroll
      for (int p = 0; p < 4; ++p) {
        float4 v4 = *(const float4*)&Vs[kk + p][c0];
        #pragma unroll
        for (int i = 0; i < 4; ++i) {
          float pw = f4get(p4[i], p);
          Oacc[i][0] += pw * v4.x;
          Oacc[i][1] += pw * v4.y;
          Oacc[i][2] += pw * v4.z;
          Oacc[i][3] += pw * v4.w;
        }
      }
    }
  }

  // epilogue: normalize and store [B,S,D]
  #pragma unroll
  for (int i = 0; i < 4; ++i) {
    float inv = 1.0f / l_i[i];
    *(float4*)(O + base + (size_t)(qt * 64 + r0 + i) * D_ + c0) =
        make_float4(Oacc[i][0] * inv, Oacc[i][1] * inv,
                    Oacc[i][2] * inv, Oacc[i][3] * inv);
  }
}

// ---------------------------------------------------------------------------
extern "C" void kernel_launch(void* const* d_in, const int* in_sizes, int n_in,
                              void* d_out, int out_size, void* d_ws, size_t ws_size,
                              hipStream_t stream)
{
  const float* x  = (const float*)d_in[0];
  const float* Wq = (const float*)d_in[1];
  const float* Wk = (const float*)d_in[2];
  const float* Wv = (const float*)d_in[3];
  const float* Wo = (const float*)d_in[4];
  const int*   tp = (const int*)d_in[5];
  float* out = (float*)d_out;

  const size_t NBUF = (size_t)B_ * S_ * D_;   // 4,194,304 floats
  float* qb = (float*)d_ws;
  float* kb = qb + NBUF;
  float* vb = kb + NBUF;
  float* ab = vb + NBUF;

  const int M = B_ * S_;   // 4096
  const int N = D_;        // 1024
  const int K = D_;        // 1024

  // QKV projections (fused: z picks W/C)
  gemm_nt<<<dim3(N / 128, M / 128, 3), 256, 0, stream>>>(
      x, Wq, Wk, Wv, qb, kb, vb, M, N, K);

  // RoPE on Q and K
  rope_kernel<<<dim3((B_ * S_ * H_ * 32) / 256, 2), 256, 0, stream>>>(qb, kb, tp);

  // causal flash attention
  attn_kernel<<<dim3(S_ / 64, B_ * H_), 256, 0, stream>>>(qb, kb, vb, ab);

  // output projection
  gemm_nt<<<dim3(N / 128, M / 128, 1), 256, 0, stream>>>(
      ab, Wo, Wo, Wo, out, out, out, M, N, K);
}

// Round 2
// 571.527 us; speedup vs baseline: 1.9714x; 1.9714x over previous
//
#include <hip/hip_runtime.h>
#include <hip/hip_bf16.h>
#include <math.h>

#define B_  2
#define S_  2048
#define H_  16
#define D_  1024
#define DK_ 64

typedef __attribute__((ext_vector_type(8))) short bf16x8;   // 8 bf16 = 4 VGPRs
typedef __attribute__((ext_vector_type(4))) float f32x4;

__device__ __forceinline__ float f4get(const float4& v, int i) {
  return (i == 0) ? v.x : (i == 1) ? v.y : (i == 2) ? v.z : v.w;
}
__device__ __forceinline__ unsigned short f2bf(float f) {
  unsigned u = __float_as_uint(f);
  unsigned r = (u + 0x7FFFu + ((u >> 16) & 1u)) >> 16;   // round-to-nearest-even
  return (unsigned short)r;
}
__device__ __forceinline__ float bf2f(unsigned short h) {
  return __uint_as_float((unsigned)h << 16);
}

// ---------------------------------------------------------------------------
// GEMM NT: C[m][n] = sum_k A[m][k] * W[n][k].  fp32 in; fp32 or bf16 out.
// 128x128 tile, TK=16, 256 threads, 2x2 quadrants of 4x4 per thread.
// blockIdx.z selects (W, C) pair for fused QKV.
// ---------------------------------------------------------------------------
__global__ __launch_bounds__(256)
void gemm_nt(const float* __restrict__ A,
             const float* __restrict__ W0, const float* __restrict__ W1,
             const float* __restrict__ W2,
             void* __restrict__ C0v, void* __restrict__ C1v,
             void* __restrict__ C2v,
             int M, int N, int K, int bf16_out)
{
  const float* W = (blockIdx.z == 0) ? W0 : (blockIdx.z == 1) ? W1 : W2;
  void*       Cv = (blockIdx.z == 0) ? C0v : (blockIdx.z == 1) ? C1v : C2v;

  __shared__ float As[16][132];
  __shared__ float Bs[16][132];

  const int tid  = threadIdx.x;
  const int tx   = tid & 15;
  const int ty   = tid >> 4;
  const int row0 = blockIdx.y * 128;
  const int col0 = blockIdx.x * 128;

  float acc[2][2][4][4];
  #pragma unroll
  for (int a = 0; a < 2; ++a)
    #pragma unroll
    for (int b = 0; b < 2; ++b)
      #pragma unroll
      for (int i = 0; i < 4; ++i)
        #pragma unroll
        for (int j = 0; j < 4; ++j) acc[a][b][i][j] = 0.f;

  for (int k0 = 0; k0 < K; k0 += 16) {
    #pragma unroll
    for (int p = 0; p < 2; ++p) {
      int idx = tid + p * 256;
      int r   = idx >> 2;
      int kk4 = (idx & 3) << 2;
      float4 av = *(const float4*)(A + (size_t)(row0 + r) * K + k0 + kk4);
      As[kk4 + 0][r] = av.x; As[kk4 + 1][r] = av.y;
      As[kk4 + 2][r] = av.z; As[kk4 + 3][r] = av.w;
      float4 wv = *(const float4*)(W + (size_t)(col0 + r) * K + k0 + kk4);
      Bs[kk4 + 0][r] = wv.x; Bs[kk4 + 1][r] = wv.y;
      Bs[kk4 + 2][r] = wv.z; Bs[kk4 + 3][r] = wv.w;
    }
    __syncthreads();

    #pragma unroll
    for (int kk = 0; kk < 16; ++kk) {
      float4 a0 = *(const float4*)&As[kk][ty * 4];
      float4 a1 = *(const float4*)&As[kk][64 + ty * 4];
      float4 b0 = *(const float4*)&Bs[kk][tx * 4];
      float4 b1 = *(const float4*)&Bs[kk][64 + tx * 4];
      #pragma unroll
      for (int i = 0; i < 4; ++i) {
        float av0 = f4get(a0, i), av1 = f4get(a1, i);
        #pragma unroll
        for (int j = 0; j < 4; ++j) {
          float bv0 = f4get(b0, j), bv1 = f4get(b1, j);
          acc[0][0][i][j] += av0 * bv0;
          acc[0][1][i][j] += av0 * bv1;
          acc[1][0][i][j] += av1 * bv0;
          acc[1][1][i][j] += av1 * bv1;
        }
      }
    }
    __syncthreads();
  }

  #pragma unroll
  for (int ih = 0; ih < 2; ++ih)
    #pragma unroll
    for (int i = 0; i < 4; ++i) {
      int row = row0 + ih * 64 + ty * 4 + i;
      #pragma unroll
      for (int jh = 0; jh < 2; ++jh) {
        int col = col0 + jh * 64 + tx * 4;
        if (bf16_out) {
          ushort4 o;
          o.x = f2bf(acc[ih][jh][i][0]); o.y = f2bf(acc[ih][jh][i][1]);
          o.z = f2bf(acc[ih][jh][i][2]); o.w = f2bf(acc[ih][jh][i][3]);
          *(ushort4*)((unsigned short*)Cv + (size_t)row * N + col) = o;
        } else {
          *(float4*)((float*)Cv + (size_t)row * N + col) =
              make_float4(acc[ih][jh][i][0], acc[ih][jh][i][1],
                          acc[ih][jh][i][2], acc[ih][jh][i][3]);
        }
      }
    }
}

// ---------------------------------------------------------------------------
// RoPE in-place on bf16 Q (grid.y==0) / K (grid.y==1), layout [B,S,D].
// ---------------------------------------------------------------------------
__global__ __launch_bounds__(256)
void rope_bf16(unsigned short* __restrict__ q, unsigned short* __restrict__ k,
               const int* __restrict__ pos)
{
  int t = blockIdx.x * 256 + threadIdx.x;        // pair id, 0..2^21-1
  unsigned short* buf = (blockIdx.y == 0) ? q : k;
  int i  = t & 31;
  int s  = (t >> 9) & 2047;
  int b  = t >> 20;
  int p  = pos[(b << 11) | s];
  float freq = __expf(-0.2878231366f * (float)i);  // 10000^(-2i/64)
  float ang  = (float)p * freq;
  float sn, cs;
  sincosf(ang, &sn, &cs);
  size_t off = ((size_t)(t >> 5) << 6) + 2 * (size_t)i;
  ushort2 v = *(ushort2*)(buf + off);
  float x = bf2f(v.x), y = bf2f(v.y);
  ushort2 r;
  r.x = f2bf(x * cs - y * sn);
  r.y = f2bf(x * sn + y * cs);
  *(ushort2*)(buf + off) = r;
}

// ---------------------------------------------------------------------------
// V transpose: vh bf16 [B,S,D] (head-sliced) -> vt bf16 [B*H, dk=64, S].
// 64(s) x 64(d) tile through padded LDS; 16B loads and stores.
// ---------------------------------------------------------------------------
__global__ __launch_bounds__(256)
void transpose_v(const unsigned short* __restrict__ vh,
                 unsigned short* __restrict__ vt)
{
  __shared__ unsigned short T[64][72];
  const int s0  = blockIdx.x * 64;
  const int bh  = blockIdx.y;
  const int b   = bh >> 4, h = bh & 15;
  const int tid = threadIdx.x;

  #pragma unroll
  for (int p = 0; p < 2; ++p) {
    int idx = tid + p * 256;          // 0..511
    int s   = idx >> 3;
    int c8  = (idx & 7) * 8;
    *(bf16x8*)&T[s][c8] =
        *(const bf16x8*)(vh + (size_t)b * S_ * D_ + (size_t)(s0 + s) * D_ +
                         h * DK_ + c8);
  }
  __syncthreads();
  #pragma unroll
  for (int p = 0; p < 2; ++p) {
    int idx = tid + p * 256;
    int d   = idx >> 3;
    int s8  = (idx & 7) * 8;
    unsigned short tmp[8];
    #pragma unroll
    for (int j = 0; j < 8; ++j) tmp[j] = T[s8 + j][d];
    *(bf16x8*)(vt + ((size_t)bh * DK_ + d) * S_ + s0 + s8) = *(bf16x8*)tmp;
  }
}

// ---------------------------------------------------------------------------
// MFMA flash attention (bf16 in, fp32 out), causal.
// Block = 4 waves, 64-q tile; wave w owns q rows qt*64+w*16..+15.
// Computes S^T = K·Q^T (C-layout puts q in lane&15 -> 2-shuffle softmax),
// then O^T = V^T·P^T.  K natural + V^T staged in LDS; P^T round-trips
// through per-wave LDS ([q][key] layout -> contiguous B-frag reads).
// ---------------------------------------------------------------------------
__global__ __launch_bounds__(256)
void attn_mfma(const unsigned short* __restrict__ Q,
               const unsigned short* __restrict__ K,
               const unsigned short* __restrict__ Vt,
               float* __restrict__ O)
{
  const int qt   = (int)gridDim.x - 1 - (int)blockIdx.x;  // big tiles first
  const int bh   = blockIdx.y;
  const int b    = bh >> 4, h = bh & 15;
  const int tid  = threadIdx.x;
  const int wave = tid >> 6;
  const int lane = tid & 63;
  const int quad = lane >> 4;
  const int col  = lane & 15;

  __shared__ unsigned short Ks[64][72];      // [key][dk]
  __shared__ unsigned short Vs[64][72];      // [dk][key]  (from vt)
  __shared__ unsigned short Pl[4][16][72];   // per-wave: [q][key]

  const size_t qkbase = (size_t)b * S_ * D_ + (size_t)h * DK_;  // row stride D
  const size_t vtbase = (size_t)bh * DK_ * S_;                  // row stride S

  // Q B-fragments: lane holds Q[qrow=base+col][c*32 + quad*8 .. +7]
  const int qrow = qt * 64 + wave * 16 + col;
  bf16x8 qf[2];
  qf[0] = *(const bf16x8*)(Q + qkbase + (size_t)qrow * D_ + quad * 8);
  qf[1] = *(const bf16x8*)(Q + qkbase + (size_t)qrow * D_ + 32 + quad * 8);

  f32x4 Oacc[4];              // O^T tile nb: row d=nb*16+quad*4+r, col q=col
  #pragma unroll
  for (int nb = 0; nb < 4; ++nb)
    #pragma unroll
    for (int r = 0; r < 4; ++r) Oacc[nb][r] = 0.f;
  float m_i = -1e30f, l_i = 0.f;

  for (int kt = 0; kt <= qt; ++kt) {
    __syncthreads();   // previous iteration's K/V reads complete
    // stage K tile (natural) and V^T tile
    #pragma unroll
    for (int p = 0; p < 2; ++p) {
      int idx = tid + p * 256;          // 0..511
      int r   = idx >> 3;
      int c8  = (idx & 7) * 8;
      *(bf16x8*)&Ks[r][c8] =
          *(const bf16x8*)(K + qkbase + (size_t)(kt * 64 + r) * D_ + c8);
      *(bf16x8*)&Vs[r][c8] =
          *(const bf16x8*)(Vt + vtbase + (size_t)r * S_ + kt * 64 + c8);
    }
    __syncthreads();

    // S^T = K · Q^T  : 4 tiles of 16 keys
    f32x4 st[4];
    #pragma unroll
    for (int nb = 0; nb < 4; ++nb) {
      bf16x8 ka0 = *(const bf16x8*)&Ks[nb * 16 + col][quad * 8];
      bf16x8 ka1 = *(const bf16x8*)&Ks[nb * 16 + col][32 + quad * 8];
      f32x4 acc;
      #pragma unroll
      for (int r = 0; r < 4; ++r) acc[r] = 0.f;
      acc = __builtin_amdgcn_mfma_f32_16x16x32_bf16(ka0, qf[0], acc, 0, 0, 0);
      acc = __builtin_amdgcn_mfma_f32_16x16x32_bf16(ka1, qf[1], acc, 0, 0, 0);
      st[nb] = acc;
    }

    // scale + causal mask (only diagonal block needs masking)
    const float SCALE = 0.125f;
    if (kt == qt) {
      const int qq = wave * 16 + col;
      #pragma unroll
      for (int nb = 0; nb < 4; ++nb)
        #pragma unroll
        for (int r = 0; r < 4; ++r) {
          int key = nb * 16 + quad * 4 + r;
          st[nb][r] = (key <= qq) ? st[nb][r] * SCALE : -1e30f;
        }
    } else {
      #pragma unroll
      for (int nb = 0; nb < 4; ++nb)
        #pragma unroll
        for (int r = 0; r < 4; ++r) st[nb][r] *= SCALE;
    }

    // online softmax: row (=q) stats live in lanes sharing col; reduce quads
    float vmax = -1e30f;
    #pragma unroll
    for (int nb = 0; nb < 4; ++nb)
      #pragma unroll
      for (int r = 0; r < 4; ++r) vmax = fmaxf(vmax, st[nb][r]);
    vmax = fmaxf(vmax, __shfl_xor(vmax, 16));
    vmax = fmaxf(vmax, __shfl_xor(vmax, 32));

    float mnew  = fmaxf(m_i, vmax);
    float alpha = __expf(m_i - mnew);
    float rsum  = 0.f;
    #pragma unroll
    for (int nb = 0; nb < 4; ++nb)
      #pragma unroll
      for (int r = 0; r < 4; ++r) {
        float pv = __expf(st[nb][r] - mnew);
        st[nb][r] = pv;
        rsum += pv;
      }
    rsum += __shfl_xor(rsum, 16);
    rsum += __shfl_xor(rsum, 32);
    m_i = mnew;
    l_i = l_i * alpha + rsum;
    #pragma unroll
    for (int nb = 0; nb < 4; ++nb) {
      #pragma unroll
      for (int r = 0; r < 4; ++r) Oacc[nb][r] *= alpha;
    }

    // P^T -> per-wave LDS as [q][key]; regs r are contiguous keys -> b64
    #pragma unroll
    for (int nb = 0; nb < 4; ++nb) {
      ushort4 pk;
      pk.x = f2bf(st[nb][0]); pk.y = f2bf(st[nb][1]);
      pk.z = f2bf(st[nb][2]); pk.w = f2bf(st[nb][3]);
      *(ushort4*)&Pl[wave][col][nb * 16 + quad * 4] = pk;
    }
    // per-wave buffer: no block barrier needed; compiler inserts lgkmcnt

    // O^T += V^T · P^T
    bf16x8 pf0 = *(const bf16x8*)&Pl[wave][col][quad * 8];
    bf16x8 pf1 = *(const bf16x8*)&Pl[wave][col][32 + quad * 8];
    #pragma unroll
    for (int nb = 0; nb < 4; ++nb) {
      bf16x8 va0 = *(const bf16x8*)&Vs[nb * 16 + col][quad * 8];
      bf16x8 va1 = *(const bf16x8*)&Vs[nb * 16 + col][32 + quad * 8];
      Oacc[nb] = __builtin_amdgcn_mfma_f32_16x16x32_bf16(va0, pf0, Oacc[nb], 0, 0, 0);
      Oacc[nb] = __builtin_amdgcn_mfma_f32_16x16x32_bf16(va1, pf1, Oacc[nb], 0, 0, 0);
    }
  }

  // epilogue: O^T[d][q] / l -> out[b][q][h*64+d], float4 along d
  const float inv = 1.0f / l_i;
  #pragma unroll
  for (int nb = 0; nb < 4; ++nb) {
    int d = nb * 16 + quad * 4;
    *(float4*)(O + (size_t)b * S_ * D_ + (size_t)qrow * D_ + h * DK_ + d) =
        make_float4(Oacc[nb][0] * inv, Oacc[nb][1] * inv,
                    Oacc[nb][2] * inv, Oacc[nb][3] * inv);
  }
}

// ---------------------------------------------------------------------------
extern "C" void kernel_launch(void* const* d_in, const int* in_sizes, int n_in,
                              void* d_out, int out_size, void* d_ws, size_t ws_size,
                              hipStream_t stream)
{
  const float* x  = (const float*)d_in[0];
  const float* Wq = (const float*)d_in[1];
  const float* Wk = (const float*)d_in[2];
  const float* Wv = (const float*)d_in[3];
  const float* Wo = (const float*)d_in[4];
  const int*   tp = (const int*)d_in[5];
  float* out = (float*)d_out;

  const size_t NTOK = (size_t)B_ * S_ * D_;     // 4,194,304 elements
  unsigned short* qh = (unsigned short*)d_ws;   // bf16 [B,S,D]
  unsigned short* kh = qh + NTOK;
  unsigned short* vh = kh + NTOK;
  unsigned short* vt = vh + NTOK;               // bf16 [B*H, 64, S]
  float*          ab = (float*)(vt + NTOK);     // fp32 [B,S,D]

  const int M = B_ * S_;   // 4096
  const int N = D_;        // 1024
  const int K = D_;        // 1024

  // QKV projections -> bf16
  gemm_nt<<<dim3(N / 128, M / 128, 3), 256, 0, stream>>>(
      x, Wq, Wk, Wv, qh, kh, vh, M, N, K, 1);

  // RoPE on bf16 Q,K
  rope_bf16<<<dim3((B_ * S_ * H_ * 32) / 256, 2), 256, 0, stream>>>(qh, kh, tp);

  // V -> V^T bf16
  transpose_v<<<dim3(S_ / 64, B_ * H_), 256, 0, stream>>>(vh, vt);

  // causal MFMA flash attention -> fp32 ab
  attn_mfma<<<dim3(S_ / 64, B_ * H_), 256, 0, stream>>>(qh, kh, vt, ab);

  // output projection (fp32 in, fp32 out)
  gemm_nt<<<dim3(N / 128, M / 128, 1), 256, 0, stream>>>(
      ab, Wo, Wo, Wo, out, out, out, M, N, K, 0);
}

// Round 3
// 244.715 us; speedup vs baseline: 4.6041x; 2.3355x over previous
//
#include <hip/hip_runtime.h>
#include <hip/hip_bf16.h>
#include <math.h>

#define B_  2
#define S_  2048
#define H_  16
#define D_  1024
#define DK_ 64

typedef __attribute__((ext_vector_type(8))) short bf16x8;   // 8 bf16 = 4 VGPRs
typedef __attribute__((ext_vector_type(8))) unsigned short ushort8v;
typedef __attribute__((ext_vector_type(4))) float f32x4;

__device__ __forceinline__ unsigned short f2bf(float f) {
  unsigned u = __float_as_uint(f);
  unsigned r = (u + 0x7FFFu + ((u >> 16) & 1u)) >> 16;   // round-to-nearest-even
  return (unsigned short)r;
}
__device__ __forceinline__ float bf2f(unsigned short h) {
  return __uint_as_float((unsigned)h << 16);
}
// async global->LDS, 16B per lane. LDS dest = wave-uniform base + lane*16.
__device__ __forceinline__ void gload_lds16(const unsigned short* g,
                                            unsigned short* l) {
  __builtin_amdgcn_global_load_lds(
      (const __attribute__((address_space(1))) unsigned int*)(const void*)g,
      (__attribute__((address_space(3))) unsigned int*)(void*)l, 16, 0, 0);
}

// ---------------------------------------------------------------------------
// Cast fp32 -> bf16 for x and the four weights. blockIdx.y selects tensor.
// ---------------------------------------------------------------------------
__global__ __launch_bounds__(256)
void cast5_bf16(const float* __restrict__ x,  const float* __restrict__ wq,
                const float* __restrict__ wk, const float* __restrict__ wv,
                const float* __restrict__ wo,
                unsigned short* __restrict__ xb,  unsigned short* __restrict__ wqb,
                unsigned short* __restrict__ wkb, unsigned short* __restrict__ wvb,
                unsigned short* __restrict__ wob)
{
  const int z = blockIdx.y;
  const float* s; unsigned short* d; int nblk;
  switch (z) {
    case 0: s = x;  d = xb;  nblk = 2048; break;
    case 1: s = wq; d = wqb; nblk = 512;  break;
    case 2: s = wk; d = wkb; nblk = 512;  break;
    case 3: s = wv; d = wvb; nblk = 512;  break;
    default: s = wo; d = wob; nblk = 512; break;
  }
  if ((int)blockIdx.x >= nblk) return;
  size_t i0 = ((size_t)blockIdx.x * 256 + threadIdx.x) * 8;
  float4 v0 = *(const float4*)(s + i0);
  float4 v1 = *(const float4*)(s + i0 + 4);
  ushort8v o;
  o[0] = f2bf(v0.x); o[1] = f2bf(v0.y); o[2] = f2bf(v0.z); o[3] = f2bf(v0.w);
  o[4] = f2bf(v1.x); o[5] = f2bf(v1.y); o[6] = f2bf(v1.z); o[7] = f2bf(v1.w);
  *(ushort8v*)(d + i0) = o;
}

// ---------------------------------------------------------------------------
// bf16 MFMA GEMM NT: C[m][n] = sum_k A[m][k] * W[n][k].
// m97 structure: 128x128 tile, BK=32, global_load_lds width-16 staging,
// 4 waves in a 2x2 grid, each owning a 64x64 patch = 4x4 MFMA 16x16x32 tiles.
// blockIdx.z selects (W, C) for fused QKV. bf16 or fp32 output.
// ---------------------------------------------------------------------------
__global__ __launch_bounds__(256)
void gemm_mfma(const unsigned short* __restrict__ A,
               const unsigned short* __restrict__ W0,
               const unsigned short* __restrict__ W1,
               const unsigned short* __restrict__ W2,
               void* __restrict__ C0v, void* __restrict__ C1v,
               void* __restrict__ C2v,
               int M, int N, int K, int bf16_out)
{
  const unsigned short* W = (blockIdx.z == 0) ? W0 : (blockIdx.z == 1) ? W1 : W2;
  void* Cv = (blockIdx.z == 0) ? C0v : (blockIdx.z == 1) ? C1v : C2v;

  __shared__ unsigned short As[128 * 32];   // [row][32], contiguous (no pad —
  __shared__ unsigned short Bs[128 * 32];   //  global_load_lds layout)

  const int tid   = threadIdx.x;
  const int wave  = tid >> 6;
  const int lane  = tid & 63;
  const int quad  = lane >> 4;
  const int col16 = lane & 15;
  const int row0  = blockIdx.y * 128;
  const int col0  = blockIdx.x * 128;
  const int wr    = (wave >> 1) * 64;       // wave row offset in tile
  const int wc    = (wave & 1) * 64;        // wave col offset in tile

  // staging: lane covers row wave*16 + lane/4 (+64 on 2nd issue), 8 elems at (lane&3)*8
  const int srow = wave * 16 + (lane >> 2);
  const int scol = (lane & 3) * 8;
  const unsigned short* gA = A + (size_t)(row0 + srow) * K + scol;
  const unsigned short* gB = W + (size_t)(col0 + srow) * K + scol;
  unsigned short* lA0 = &As[(wave * 16) * 32];
  unsigned short* lA1 = &As[(wave * 16 + 64) * 32];
  unsigned short* lB0 = &Bs[(wave * 16) * 32];
  unsigned short* lB1 = &Bs[(wave * 16 + 64) * 32];

  f32x4 acc[4][4];
  #pragma unroll
  for (int mt = 0; mt < 4; ++mt)
    #pragma unroll
    for (int nt = 0; nt < 4; ++nt)
      #pragma unroll
      for (int r = 0; r < 4; ++r) acc[mt][nt][r] = 0.f;

  for (int k0 = 0; k0 < K; k0 += 32) {
    __syncthreads();   // previous iteration's ds_reads complete
    gload_lds16(gA + k0,              lA0);
    gload_lds16(gA + (size_t)64 * K + k0, lA1);
    gload_lds16(gB + k0,              lB0);
    gload_lds16(gB + (size_t)64 * K + k0, lB1);
    __syncthreads();   // drains vmcnt(0): staging visible

    bf16x8 af[4], bfr[4];
    #pragma unroll
    for (int mt = 0; mt < 4; ++mt)
      af[mt] = *(const bf16x8*)&As[(wr + mt * 16 + col16) * 32 + quad * 8];
    #pragma unroll
    for (int nt = 0; nt < 4; ++nt)
      bfr[nt] = *(const bf16x8*)&Bs[(wc + nt * 16 + col16) * 32 + quad * 8];

    #pragma unroll
    for (int mt = 0; mt < 4; ++mt)
      #pragma unroll
      for (int nt = 0; nt < 4; ++nt)
        acc[mt][nt] = __builtin_amdgcn_mfma_f32_16x16x32_bf16(
            af[mt], bfr[nt], acc[mt][nt], 0, 0, 0);
  }

  // epilogue: C[row=quad*4+r (within 16-tile)][col=col16]
  #pragma unroll
  for (int mt = 0; mt < 4; ++mt)
    #pragma unroll
    for (int r = 0; r < 4; ++r) {
      int row = row0 + wr + mt * 16 + quad * 4 + r;
      #pragma unroll
      for (int nt = 0; nt < 4; ++nt) {
        int col = col0 + wc + nt * 16 + col16;
        if (bf16_out)
          ((unsigned short*)Cv)[(size_t)row * N + col] = f2bf(acc[mt][nt][r]);
        else
          ((float*)Cv)[(size_t)row * N + col] = acc[mt][nt][r];
      }
    }
}

// ---------------------------------------------------------------------------
// RoPE in-place on bf16 Q (grid.y==0) / K (grid.y==1), layout [B,S,D].
// ---------------------------------------------------------------------------
__global__ __launch_bounds__(256)
void rope_bf16(unsigned short* __restrict__ q, unsigned short* __restrict__ k,
               const int* __restrict__ pos)
{
  int t = blockIdx.x * 256 + threadIdx.x;        // pair id
  unsigned short* buf = (blockIdx.y == 0) ? q : k;
  int i  = t & 31;
  int s  = (t >> 9) & 2047;
  int b  = t >> 20;
  int p  = pos[(b << 11) | s];
  float freq = __expf(-0.2878231366f * (float)i);  // 10000^(-2i/64)
  float ang  = (float)p * freq;
  float sn, cs;
  sincosf(ang, &sn, &cs);
  size_t off = ((size_t)(t >> 5) << 6) + 2 * (size_t)i;
  ushort2 v = *(ushort2*)(buf + off);
  float x = bf2f(v.x), y = bf2f(v.y);
  ushort2 r;
  r.x = f2bf(x * cs - y * sn);
  r.y = f2bf(x * sn + y * cs);
  *(ushort2*)(buf + off) = r;
}

// ---------------------------------------------------------------------------
// V transpose: vh bf16 [B,S,D] (head-sliced) -> vt bf16 [B*H, dk=64, S].
// ---------------------------------------------------------------------------
__global__ __launch_bounds__(256)
void transpose_v(const unsigned short* __restrict__ vh,
                 unsigned short* __restrict__ vt)
{
  __shared__ unsigned short T[64][72];
  const int s0  = blockIdx.x * 64;
  const int bh  = blockIdx.y;
  const int b   = bh >> 4, h = bh & 15;
  const int tid = threadIdx.x;

  #pragma unroll
  for (int p = 0; p < 2; ++p) {
    int idx = tid + p * 256;
    int s   = idx >> 3;
    int c8  = (idx & 7) * 8;
    *(bf16x8*)&T[s][c8] =
        *(const bf16x8*)(vh + (size_t)b * S_ * D_ + (size_t)(s0 + s) * D_ +
                         h * DK_ + c8);
  }
  __syncthreads();
  #pragma unroll
  for (int p = 0; p < 2; ++p) {
    int idx = tid + p * 256;
    int d   = idx >> 3;
    int s8  = (idx & 7) * 8;
    unsigned short tmp[8];
    #pragma unroll
    for (int j = 0; j < 8; ++j) tmp[j] = T[s8 + j][d];
    *(bf16x8*)(vt + ((size_t)bh * DK_ + d) * S_ + s0 + s8) = *(bf16x8*)tmp;
  }
}

// ---------------------------------------------------------------------------
// MFMA flash attention (bf16 in, bf16 out), causal.
// S^T = K·Q^T (softmax row = lane&15 -> 2-shuffle reduce), O^T = V^T·P^T.
// ---------------------------------------------------------------------------
__global__ __launch_bounds__(256)
void attn_mfma(const unsigned short* __restrict__ Q,
               const unsigned short* __restrict__ K,
               const unsigned short* __restrict__ Vt,
               unsigned short* __restrict__ O)
{
  const int qt   = (int)gridDim.x - 1 - (int)blockIdx.x;  // big tiles first
  const int bh   = blockIdx.y;
  const int b    = bh >> 4, h = bh & 15;
  const int tid  = threadIdx.x;
  const int wave = tid >> 6;
  const int lane = tid & 63;
  const int quad = lane >> 4;
  const int col  = lane & 15;

  __shared__ unsigned short Ks[64][72];      // [key][dk]
  __shared__ unsigned short Vs[64][72];      // [dk][key]
  __shared__ unsigned short Pl[4][16][72];   // per-wave [q][key]

  const size_t qkbase = (size_t)b * S_ * D_ + (size_t)h * DK_;
  const size_t vtbase = (size_t)bh * DK_ * S_;

  const int qrow = qt * 64 + wave * 16 + col;
  bf16x8 qf[2];
  qf[0] = *(const bf16x8*)(Q + qkbase + (size_t)qrow * D_ + quad * 8);
  qf[1] = *(const bf16x8*)(Q + qkbase + (size_t)qrow * D_ + 32 + quad * 8);

  f32x4 Oacc[4];
  #pragma unroll
  for (int nb = 0; nb < 4; ++nb)
    #pragma unroll
    for (int r = 0; r < 4; ++r) Oacc[nb][r] = 0.f;
  float m_i = -1e30f, l_i = 0.f;

  for (int kt = 0; kt <= qt; ++kt) {
    __syncthreads();
    #pragma unroll
    for (int p = 0; p < 2; ++p) {
      int idx = tid + p * 256;
      int r   = idx >> 3;
      int c8  = (idx & 7) * 8;
      *(bf16x8*)&Ks[r][c8] =
          *(const bf16x8*)(K + qkbase + (size_t)(kt * 64 + r) * D_ + c8);
      *(bf16x8*)&Vs[r][c8] =
          *(const bf16x8*)(Vt + vtbase + (size_t)r * S_ + kt * 64 + c8);
    }
    __syncthreads();

    f32x4 st[4];
    #pragma unroll
    for (int nb = 0; nb < 4; ++nb) {
      bf16x8 ka0 = *(const bf16x8*)&Ks[nb * 16 + col][quad * 8];
      bf16x8 ka1 = *(const bf16x8*)&Ks[nb * 16 + col][32 + quad * 8];
      f32x4 a;
      #pragma unroll
      for (int r = 0; r < 4; ++r) a[r] = 0.f;
      a = __builtin_amdgcn_mfma_f32_16x16x32_bf16(ka0, qf[0], a, 0, 0, 0);
      a = __builtin_amdgcn_mfma_f32_16x16x32_bf16(ka1, qf[1], a, 0, 0, 0);
      st[nb] = a;
    }

    const float SCALE = 0.125f;
    if (kt == qt) {
      const int qq = wave * 16 + col;
      #pragma unroll
      for (int nb = 0; nb < 4; ++nb)
        #pragma unroll
        for (int r = 0; r < 4; ++r) {
          int key = nb * 16 + quad * 4 + r;
          st[nb][r] = (key <= qq) ? st[nb][r] * SCALE : -1e30f;
        }
    } else {
      #pragma unroll
      for (int nb = 0; nb < 4; ++nb)
        #pragma unroll
        for (int r = 0; r < 4; ++r) st[nb][r] *= SCALE;
    }

    float vmax = -1e30f;
    #pragma unroll
    for (int nb = 0; nb < 4; ++nb)
      #pragma unroll
      for (int r = 0; r < 4; ++r) vmax = fmaxf(vmax, st[nb][r]);
    vmax = fmaxf(vmax, __shfl_xor(vmax, 16));
    vmax = fmaxf(vmax, __shfl_xor(vmax, 32));

    float mnew  = fmaxf(m_i, vmax);
    float alpha = __expf(m_i - mnew);
    float rsum  = 0.f;
    #pragma unroll
    for (int nb = 0; nb < 4; ++nb)
      #pragma unroll
      for (int r = 0; r < 4; ++r) {
        float pv = __expf(st[nb][r] - mnew);
        st[nb][r] = pv;
        rsum += pv;
      }
    rsum += __shfl_xor(rsum, 16);
    rsum += __shfl_xor(rsum, 32);
    m_i = mnew;
    l_i = l_i * alpha + rsum;
    #pragma unroll
    for (int nb = 0; nb < 4; ++nb)
      #pragma unroll
      for (int r = 0; r < 4; ++r) Oacc[nb][r] *= alpha;

    #pragma unroll
    for (int nb = 0; nb < 4; ++nb) {
      ushort4 pk;
      pk.x = f2bf(st[nb][0]); pk.y = f2bf(st[nb][1]);
      pk.z = f2bf(st[nb][2]); pk.w = f2bf(st[nb][3]);
      *(ushort4*)&Pl[wave][col][nb * 16 + quad * 4] = pk;
    }

    bf16x8 pf0 = *(const bf16x8*)&Pl[wave][col][quad * 8];
    bf16x8 pf1 = *(const bf16x8*)&Pl[wave][col][32 + quad * 8];
    #pragma unroll
    for (int nb = 0; nb < 4; ++nb) {
      bf16x8 va0 = *(const bf16x8*)&Vs[nb * 16 + col][quad * 8];
      bf16x8 va1 = *(const bf16x8*)&Vs[nb * 16 + col][32 + quad * 8];
      Oacc[nb] = __builtin_amdgcn_mfma_f32_16x16x32_bf16(va0, pf0, Oacc[nb], 0, 0, 0);
      Oacc[nb] = __builtin_amdgcn_mfma_f32_16x16x32_bf16(va1, pf1, Oacc[nb], 0, 0, 0);
    }
  }

  const float inv = 1.0f / l_i;
  #pragma unroll
  for (int nb = 0; nb < 4; ++nb) {
    int d = nb * 16 + quad * 4;
    ushort4 o;
    o.x = f2bf(Oacc[nb][0] * inv); o.y = f2bf(Oacc[nb][1] * inv);
    o.z = f2bf(Oacc[nb][2] * inv); o.w = f2bf(Oacc[nb][3] * inv);
    *(ushort4*)(O + (size_t)b * S_ * D_ + (size_t)qrow * D_ + h * DK_ + d) = o;
  }
}

// ---------------------------------------------------------------------------
extern "C" void kernel_launch(void* const* d_in, const int* in_sizes, int n_in,
                              void* d_out, int out_size, void* d_ws, size_t ws_size,
                              hipStream_t stream)
{
  const float* x  = (const float*)d_in[0];
  const float* Wq = (const float*)d_in[1];
  const float* Wk = (const float*)d_in[2];
  const float* Wv = (const float*)d_in[3];
  const float* Wo = (const float*)d_in[4];
  const int*   tp = (const int*)d_in[5];
  float* out = (float*)d_out;

  const size_t NTOK = (size_t)B_ * S_ * D_;     // 4,194,304 elements
  const size_t NW   = (size_t)D_ * D_;          // 1,048,576
  unsigned short* qh  = (unsigned short*)d_ws;  // bf16 [B,S,D]
  unsigned short* kh  = qh + NTOK;
  unsigned short* vh  = kh + NTOK;              // later reused as ab
  unsigned short* vt  = vh + NTOK;              // bf16 [B*H, 64, S]
  unsigned short* xb  = vt + NTOK;              // bf16 [B,S,D]
  unsigned short* wqb = xb + NTOK;
  unsigned short* wkb = wqb + NW;
  unsigned short* wvb = wkb + NW;
  unsigned short* wob = wvb + NW;
  unsigned short* ab  = vh;                     // alias: vh dead after transpose

  const int M = B_ * S_;   // 4096
  const int N = D_;        // 1024
  const int K = D_;        // 1024

  // fp32 -> bf16 casts
  cast5_bf16<<<dim3(2048, 5), 256, 0, stream>>>(
      x, Wq, Wk, Wv, Wo, xb, wqb, wkb, wvb, wob);

  // QKV projections (MFMA) -> bf16
  gemm_mfma<<<dim3(N / 128, M / 128, 3), 256, 0, stream>>>(
      xb, wqb, wkb, wvb, qh, kh, vh, M, N, K, 1);

  // RoPE on bf16 Q,K
  rope_bf16<<<dim3((B_ * S_ * H_ * 32) / 256, 2), 256, 0, stream>>>(qh, kh, tp);

  // V -> V^T bf16
  transpose_v<<<dim3(S_ / 64, B_ * H_), 256, 0, stream>>>(vh, vt);

  // causal MFMA flash attention -> bf16 ab (overwrites vh)
  attn_mfma<<<dim3(S_ / 64, B_ * H_), 256, 0, stream>>>(qh, kh, vt, ab);

  // output projection (MFMA) -> fp32 out
  gemm_mfma<<<dim3(N / 128, M / 128, 1), 256, 0, stream>>>(
      ab, wob, wob, wob, out, out, out, M, N, K, 0);
}

// Round 4
// 220.363 us; speedup vs baseline: 5.1129x; 1.1105x over previous
//
#include <hip/hip_runtime.h>
#include <hip/hip_bf16.h>
#include <math.h>

#define B_  2
#define S_  2048
#define H_  16
#define D_  1024
#define DK_ 64

typedef __attribute__((ext_vector_type(8))) short bf16x8;   // 8 bf16 = 4 VGPRs
typedef __attribute__((ext_vector_type(8))) unsigned short ushort8v;
typedef __attribute__((ext_vector_type(4))) float f32x4;

__device__ __forceinline__ unsigned short f2bf(float f) {
  unsigned u = __float_as_uint(f);
  unsigned r = (u + 0x7FFFu + ((u >> 16) & 1u)) >> 16;   // RNE
  return (unsigned short)r;
}
__device__ __forceinline__ float bf2f(unsigned short h) {
  return __uint_as_float((unsigned)h << 16);
}
// truncation pack: two fp32 -> packed bf16x2 (P in [0,1]; bias ~2^-9, OK)
__device__ __forceinline__ unsigned pack_trunc(float lo, float hi) {
  return (__float_as_uint(lo) >> 16) | (__float_as_uint(hi) & 0xffff0000u);
}
__device__ __forceinline__ float fast_exp2(float x) {
#if __has_builtin(__builtin_amdgcn_exp2f)
  return __builtin_amdgcn_exp2f(x);
#else
  return __expf(x * 0.69314718056f);
#endif
}
// async global->LDS, 16B/lane. LDS dest = wave-uniform base + lane*16.
__device__ __forceinline__ void gload_lds16(const unsigned short* g,
                                            unsigned short* l) {
  __builtin_amdgcn_global_load_lds(
      (const __attribute__((address_space(1))) unsigned int*)(const void*)g,
      (__attribute__((address_space(3))) unsigned int*)(void*)l, 16, 0, 0);
}

// ---------------------------------------------------------------------------
// Cast fp32 -> bf16 for x and the four weights. blockIdx.y selects tensor.
// ---------------------------------------------------------------------------
__global__ __launch_bounds__(256)
void cast5_bf16(const float* __restrict__ x,  const float* __restrict__ wq,
                const float* __restrict__ wk, const float* __restrict__ wv,
                const float* __restrict__ wo,
                unsigned short* __restrict__ xb,  unsigned short* __restrict__ wqb,
                unsigned short* __restrict__ wkb, unsigned short* __restrict__ wvb,
                unsigned short* __restrict__ wob)
{
  const int z = blockIdx.y;
  const float* s; unsigned short* d; int nblk;
  switch (z) {
    case 0: s = x;  d = xb;  nblk = 2048; break;
    case 1: s = wq; d = wqb; nblk = 512;  break;
    case 2: s = wk; d = wkb; nblk = 512;  break;
    case 3: s = wv; d = wvb; nblk = 512;  break;
    default: s = wo; d = wob; nblk = 512; break;
  }
  if ((int)blockIdx.x >= nblk) return;
  size_t i0 = ((size_t)blockIdx.x * 256 + threadIdx.x) * 8;
  float4 v0 = *(const float4*)(s + i0);
  float4 v1 = *(const float4*)(s + i0 + 4);
  ushort8v o;
  o[0] = f2bf(v0.x); o[1] = f2bf(v0.y); o[2] = f2bf(v0.z); o[3] = f2bf(v0.w);
  o[4] = f2bf(v1.x); o[5] = f2bf(v1.y); o[6] = f2bf(v1.z); o[7] = f2bf(v1.w);
  *(ushort8v*)(d + i0) = o;
}

// ---------------------------------------------------------------------------
// bf16 MFMA GEMM NT (m97 structure), XOR-swizzled LDS slots:
// phys slot(r, j) = r*4 + (j ^ (r&3)), 8-short slots -> 2-way max on reads.
// ---------------------------------------------------------------------------
__global__ __launch_bounds__(256)
void gemm_mfma(const unsigned short* __restrict__ A,
               const unsigned short* __restrict__ W0,
               const unsigned short* __restrict__ W1,
               const unsigned short* __restrict__ W2,
               void* __restrict__ C0v, void* __restrict__ C1v,
               void* __restrict__ C2v,
               int M, int N, int K, int bf16_out)
{
  const unsigned short* W = (blockIdx.z == 0) ? W0 : (blockIdx.z == 1) ? W1 : W2;
  void* Cv = (blockIdx.z == 0) ? C0v : (blockIdx.z == 1) ? C1v : C2v;

  __shared__ unsigned short As[128 * 32];
  __shared__ unsigned short Bs[128 * 32];

  const int tid   = threadIdx.x;
  const int wave  = tid >> 6;
  const int lane  = tid & 63;
  const int quad  = lane >> 4;
  const int col16 = lane & 15;
  const int row0  = blockIdx.y * 128;
  const int col0  = blockIdx.x * 128;
  const int wr    = (wave >> 1) * 64;
  const int wc    = (wave & 1) * 64;

  // staging: lane -> phys slot = (wave*64+lane); logical (row, octet):
  const int srow = wave * 16 + (lane >> 2);
  const int scol = ((lane & 3) ^ ((lane >> 2) & 3)) * 8;   // XOR swizzle
  const unsigned short* gA = A + (size_t)(row0 + srow) * K + scol;
  const unsigned short* gB = W + (size_t)(col0 + srow) * K + scol;
  unsigned short* lA0 = &As[(wave * 16) * 32];
  unsigned short* lA1 = &As[(wave * 16 + 64) * 32];
  unsigned short* lB0 = &Bs[(wave * 16) * 32];
  unsigned short* lB1 = &Bs[(wave * 16 + 64) * 32];

  f32x4 acc[4][4];
  #pragma unroll
  for (int mt = 0; mt < 4; ++mt)
    #pragma unroll
    for (int nt = 0; nt < 4; ++nt)
      #pragma unroll
      for (int r = 0; r < 4; ++r) acc[mt][nt][r] = 0.f;

  const int jx = (quad ^ (col16 & 3)) * 8;   // swizzled frag octet

  for (int k0 = 0; k0 < K; k0 += 32) {
    __syncthreads();
    gload_lds16(gA + k0,                  lA0);
    gload_lds16(gA + (size_t)64 * K + k0, lA1);
    gload_lds16(gB + k0,                  lB0);
    gload_lds16(gB + (size_t)64 * K + k0, lB1);
    __syncthreads();

    bf16x8 af[4], bfr[4];
    #pragma unroll
    for (int mt = 0; mt < 4; ++mt)
      af[mt] = *(const bf16x8*)&As[(wr + mt * 16 + col16) * 32 + jx];
    #pragma unroll
    for (int nt = 0; nt < 4; ++nt)
      bfr[nt] = *(const bf16x8*)&Bs[(wc + nt * 16 + col16) * 32 + jx];

    #pragma unroll
    for (int mt = 0; mt < 4; ++mt)
      #pragma unroll
      for (int nt = 0; nt < 4; ++nt)
        acc[mt][nt] = __builtin_amdgcn_mfma_f32_16x16x32_bf16(
            af[mt], bfr[nt], acc[mt][nt], 0, 0, 0);
  }

  #pragma unroll
  for (int mt = 0; mt < 4; ++mt)
    #pragma unroll
    for (int r = 0; r < 4; ++r) {
      int row = row0 + wr + mt * 16 + quad * 4 + r;
      #pragma unroll
      for (int nt = 0; nt < 4; ++nt) {
        int col = col0 + wc + nt * 16 + col16;
        if (bf16_out)
          ((unsigned short*)Cv)[(size_t)row * N + col] = f2bf(acc[mt][nt][r]);
        else
          ((float*)Cv)[(size_t)row * N + col] = acc[mt][nt][r];
      }
    }
}

// ---------------------------------------------------------------------------
// RoPE in-place on bf16 Q / K. Q additionally pre-scaled by 0.125*log2(e)
// so attention scores come out in the exp2 domain, pre-scaled.
// ---------------------------------------------------------------------------
__global__ __launch_bounds__(256)
void rope_bf16(unsigned short* __restrict__ q, unsigned short* __restrict__ k,
               const int* __restrict__ pos)
{
  int t = blockIdx.x * 256 + threadIdx.x;        // pair id
  const int isQ = (blockIdx.y == 0);
  unsigned short* buf = isQ ? q : k;
  const float qs = isQ ? 0.1803368801111204f : 1.0f;  // 0.125*log2(e)
  int i  = t & 31;
  int s  = (t >> 9) & 2047;
  int b  = t >> 20;
  int p  = pos[(b << 11) | s];
  float freq = __expf(-0.2878231366f * (float)i);  // 10000^(-2i/64)
  float ang  = (float)p * freq;
  float sn, cs;
  sincosf(ang, &sn, &cs);
  size_t off = ((size_t)(t >> 5) << 6) + 2 * (size_t)i;
  ushort2 v = *(ushort2*)(buf + off);
  float x = bf2f(v.x), y = bf2f(v.y);
  ushort2 r;
  r.x = f2bf((x * cs - y * sn) * qs);
  r.y = f2bf((x * sn + y * cs) * qs);
  *(ushort2*)(buf + off) = r;
}

// ---------------------------------------------------------------------------
// V transpose: vh bf16 [B,S,D] (head-sliced) -> vt bf16 [B*H, dk=64, S].
// Pad 70 (odd word stride) -> 2-way max on the scalar gather.
// ---------------------------------------------------------------------------
__global__ __launch_bounds__(256)
void transpose_v(const unsigned short* __restrict__ vh,
                 unsigned short* __restrict__ vt)
{
  __shared__ unsigned short T[64][70];
  const int s0  = blockIdx.x * 64;
  const int bh  = blockIdx.y;
  const int b   = bh >> 4, h = bh & 15;
  const int tid = threadIdx.x;

  #pragma unroll
  for (int p = 0; p < 2; ++p) {
    int idx = tid + p * 256;
    int s   = idx >> 3;
    int c8  = (idx & 7) * 8;
    *(bf16x8*)&T[s][c8] =
        *(const bf16x8*)(vh + (size_t)b * S_ * D_ + (size_t)(s0 + s) * D_ +
                         h * DK_ + c8);
  }
  __syncthreads();
  #pragma unroll
  for (int p = 0; p < 2; ++p) {
    int idx = tid + p * 256;
    int d   = idx >> 3;
    int s8  = (idx & 7) * 8;
    unsigned short tmp[8];
    #pragma unroll
    for (int j = 0; j < 8; ++j) tmp[j] = T[s8 + j][d];
    *(bf16x8*)(vt + ((size_t)bh * DK_ + d) * S_ + s0 + s8) = *(bf16x8*)tmp;
  }
}

// ---------------------------------------------------------------------------
// One tile-side of paired flash attention: QK^T (S^T layout), online softmax
// (exp2 domain; Q pre-scaled), P pack, PV. K/V in XOR-swizzled LDS slots:
// phys slot(r, j) = r*8 + (j ^ (r&7)), 8-short slots.
// ---------------------------------------------------------------------------
__device__ __forceinline__ void attn_side(
    const unsigned short* __restrict__ Ks, const unsigned short* __restrict__ Vs,
    unsigned short (* __restrict__ Pl)[72],
    const bf16x8* qf, f32x4* Oacc, float& m_i, float& l_i,
    int quad, int col, int qlocal, bool diag)
{
  const int jx = quad ^ (col & 7);
  f32x4 st[4];
  #pragma unroll
  for (int nb = 0; nb < 4; ++nb) {
    const int s0 = (nb * 16 + col) * 8 + jx;
    bf16x8 ka0 = *(const bf16x8*)(Ks + s0 * 8);
    bf16x8 ka1 = *(const bf16x8*)(Ks + (s0 ^ 4) * 8);
    f32x4 a = {0.f, 0.f, 0.f, 0.f};
    a = __builtin_amdgcn_mfma_f32_16x16x32_bf16(ka0, qf[0], a, 0, 0, 0);
    a = __builtin_amdgcn_mfma_f32_16x16x32_bf16(ka1, qf[1], a, 0, 0, 0);
    st[nb] = a;
  }

  if (diag) {
    #pragma unroll
    for (int nb = 0; nb < 4; ++nb)
      #pragma unroll
      for (int r = 0; r < 4; ++r)
        if (nb * 16 + quad * 4 + r > qlocal) st[nb][r] = -1e30f;
  }

  float vmax = -1e30f;
  #pragma unroll
  for (int nb = 0; nb < 4; ++nb)
    #pragma unroll
    for (int r = 0; r < 4; ++r) vmax = fmaxf(vmax, st[nb][r]);
  vmax = fmaxf(vmax, __shfl_xor(vmax, 16));
  vmax = fmaxf(vmax, __shfl_xor(vmax, 32));

  float mnew  = fmaxf(m_i, vmax);
  float alpha = fast_exp2(m_i - mnew);
  float rsum  = 0.f;
  #pragma unroll
  for (int nb = 0; nb < 4; ++nb)
    #pragma unroll
    for (int r = 0; r < 4; ++r) {
      float pv = fast_exp2(st[nb][r] - mnew);
      st[nb][r] = pv;
      rsum += pv;
    }
  rsum += __shfl_xor(rsum, 16);
  rsum += __shfl_xor(rsum, 32);
  m_i = mnew;
  l_i = l_i * alpha + rsum;
  #pragma unroll
  for (int nb = 0; nb < 4; ++nb)
    #pragma unroll
    for (int r = 0; r < 4; ++r) Oacc[nb][r] *= alpha;

  #pragma unroll
  for (int nb = 0; nb < 4; ++nb) {
    uint2 pk;
    pk.x = pack_trunc(st[nb][0], st[nb][1]);
    pk.y = pack_trunc(st[nb][2], st[nb][3]);
    *(uint2*)&Pl[col][nb * 16 + quad * 4] = pk;
  }

  bf16x8 pf0 = *(const bf16x8*)&Pl[col][quad * 8];
  bf16x8 pf1 = *(const bf16x8*)&Pl[col][32 + quad * 8];
  #pragma unroll
  for (int nb = 0; nb < 4; ++nb) {
    const int s0 = (nb * 16 + col) * 8 + jx;
    bf16x8 va0 = *(const bf16x8*)(Vs + s0 * 8);
    bf16x8 va1 = *(const bf16x8*)(Vs + (s0 ^ 4) * 8);
    Oacc[nb] = __builtin_amdgcn_mfma_f32_16x16x32_bf16(va0, pf0, Oacc[nb], 0, 0, 0);
    Oacc[nb] = __builtin_amdgcn_mfma_f32_16x16x32_bf16(va1, pf1, Oacc[nb], 0, 0, 0);
  }
}

// ---------------------------------------------------------------------------
// Paired MFMA flash attention: block handles q-tiles (i, 31-i) of one bh.
// Uniform 33 tile-computations per block -> perfect CU balance.
// ---------------------------------------------------------------------------
__global__ __launch_bounds__(256)
void attn_mfma(const unsigned short* __restrict__ Q,
               const unsigned short* __restrict__ K,
               const unsigned short* __restrict__ Vt,
               unsigned short* __restrict__ O)
{
  const int qtA  = blockIdx.x;        // 0..15
  const int qtB  = 31 - qtA;
  const int bh   = blockIdx.y;
  const int b    = bh >> 4, h = bh & 15;
  const int tid  = threadIdx.x;
  const int wave = tid >> 6;
  const int lane = tid & 63;
  const int quad = lane >> 4;
  const int col  = lane & 15;
  const int qlocal = wave * 16 + col;

  __shared__ unsigned short Ks[512 * 8];     // swizzled 16B slots
  __shared__ unsigned short Vs[512 * 8];
  __shared__ unsigned short PlA[4][16][72];
  __shared__ unsigned short PlB[4][16][72];

  const size_t qkbase = (size_t)b * S_ * D_ + (size_t)h * DK_;
  const size_t vtbase = (size_t)bh * DK_ * S_;

  const int qrowA = qtA * 64 + qlocal;
  const int qrowB = qtB * 64 + qlocal;
  bf16x8 qfA[2], qfB[2];
  qfA[0] = *(const bf16x8*)(Q + qkbase + (size_t)qrowA * D_ + quad * 8);
  qfA[1] = *(const bf16x8*)(Q + qkbase + (size_t)qrowA * D_ + 32 + quad * 8);
  qfB[0] = *(const bf16x8*)(Q + qkbase + (size_t)qrowB * D_ + quad * 8);
  qfB[1] = *(const bf16x8*)(Q + qkbase + (size_t)qrowB * D_ + 32 + quad * 8);

  // staging source (slot = p*256 + tid): row = p*32 + sr, octet sj
  const int sr = tid >> 3;
  const int sj = (tid & 7) ^ (sr & 7);
  const unsigned short* gK = K + qkbase + (size_t)sr * D_ + sj * 8;
  const unsigned short* gV = Vt + vtbase + (size_t)sr * S_ + sj * 8;
  unsigned short* ldsK[2] = { &Ks[(wave * 64) * 8], &Ks[(256 + wave * 64) * 8] };
  unsigned short* ldsV[2] = { &Vs[(wave * 64) * 8], &Vs[(256 + wave * 64) * 8] };

  f32x4 OaccA[4], OaccB[4];
  #pragma unroll
  for (int nb = 0; nb < 4; ++nb)
    #pragma unroll
    for (int r = 0; r < 4; ++r) { OaccA[nb][r] = 0.f; OaccB[nb][r] = 0.f; }
  float mA = -1e30f, lA = 0.f, mB = -1e30f, lB = 0.f;

  for (int kt = 0; kt <= qtB; ++kt) {
    __syncthreads();   // previous iteration's frag reads done
    #pragma unroll
    for (int p = 0; p < 2; ++p) {
      gload_lds16(gK + (size_t)(kt * 64 + p * 32) * D_, ldsK[p]);
      gload_lds16(gV + (size_t)(p * 32) * S_ + kt * 64, ldsV[p]);
    }
    __syncthreads();   // staging visible

    attn_side(Ks, Vs, PlB[wave], qfB, OaccB, mB, lB, quad, col, qlocal,
              kt == qtB);
    if (kt <= qtA)
      attn_side(Ks, Vs, PlA[wave], qfA, OaccA, mA, lA, quad, col, qlocal,
                kt == qtA);
  }

  const float invA = 1.0f / lA;
  const float invB = 1.0f / lB;
  #pragma unroll
  for (int nb = 0; nb < 4; ++nb) {
    int d = nb * 16 + quad * 4;
    ushort4 oa, ob;
    oa.x = f2bf(OaccA[nb][0] * invA); oa.y = f2bf(OaccA[nb][1] * invA);
    oa.z = f2bf(OaccA[nb][2] * invA); oa.w = f2bf(OaccA[nb][3] * invA);
    ob.x = f2bf(OaccB[nb][0] * invB); ob.y = f2bf(OaccB[nb][1] * invB);
    ob.z = f2bf(OaccB[nb][2] * invB); ob.w = f2bf(OaccB[nb][3] * invB);
    *(ushort4*)(O + (size_t)b * S_ * D_ + (size_t)qrowA * D_ + h * DK_ + d) = oa;
    *(ushort4*)(O + (size_t)b * S_ * D_ + (size_t)qrowB * D_ + h * DK_ + d) = ob;
  }
}

// ---------------------------------------------------------------------------
extern "C" void kernel_launch(void* const* d_in, const int* in_sizes, int n_in,
                              void* d_out, int out_size, void* d_ws, size_t ws_size,
                              hipStream_t stream)
{
  const float* x  = (const float*)d_in[0];
  const float* Wq = (const float*)d_in[1];
  const float* Wk = (const float*)d_in[2];
  const float* Wv = (const float*)d_in[3];
  const float* Wo = (const float*)d_in[4];
  const int*   tp = (const int*)d_in[5];
  float* out = (float*)d_out;

  const size_t NTOK = (size_t)B_ * S_ * D_;     // 4,194,304 elements
  const size_t NW   = (size_t)D_ * D_;          // 1,048,576
  unsigned short* qh  = (unsigned short*)d_ws;  // bf16 [B,S,D]
  unsigned short* kh  = qh + NTOK;
  unsigned short* vh  = kh + NTOK;              // later reused as ab
  unsigned short* vt  = vh + NTOK;              // bf16 [B*H, 64, S]
  unsigned short* xb  = vt + NTOK;              // bf16 [B,S,D]
  unsigned short* wqb = xb + NTOK;
  unsigned short* wkb = wqb + NW;
  unsigned short* wvb = wkb + NW;
  unsigned short* wob = wvb + NW;
  unsigned short* ab  = vh;                     // alias: vh dead after transpose

  const int M = B_ * S_;   // 4096
  const int N = D_;        // 1024
  const int K = D_;        // 1024

  // fp32 -> bf16 casts
  cast5_bf16<<<dim3(2048, 5), 256, 0, stream>>>(
      x, Wq, Wk, Wv, Wo, xb, wqb, wkb, wvb, wob);

  // QKV projections (MFMA) -> bf16
  gemm_mfma<<<dim3(N / 128, M / 128, 3), 256, 0, stream>>>(
      xb, wqb, wkb, wvb, qh, kh, vh, M, N, K, 1);

  // RoPE on bf16 Q,K (Q pre-scaled by 0.125*log2e)
  rope_bf16<<<dim3((B_ * S_ * H_ * 32) / 256, 2), 256, 0, stream>>>(qh, kh, tp);

  // V -> V^T bf16
  transpose_v<<<dim3(S_ / 64, B_ * H_), 256, 0, stream>>>(vh, vt);

  // paired causal MFMA flash attention -> bf16 ab (overwrites vh)
  attn_mfma<<<dim3(16, B_ * H_), 256, 0, stream>>>(qh, kh, vt, ab);

  // output projection (MFMA) -> fp32 out
  gemm_mfma<<<dim3(N / 128, M / 128, 1), 256, 0, stream>>>(
      ab, wob, wob, wob, out, out, out, M, N, K, 0);
}